// Round 5
// baseline (459.385 us; speedup 1.0000x reference)
//
#include <hip/hip_runtime.h>

// B=128 trajectories, N=20000 vars, M=85400 clauses, K=3 literals/clause.
// Inputs: v(B*N) f32, xl(B*M) f32, xs(B*M) f32, param(6) f32,
//         input_sign(B*M*K) f32, input_idx(B*M*K) i32
// Outputs concat: C(B*M), grad_v(B*N), dxl(B*M), dxs(B*M)  -- all f32

#define NMAX 20000     // sv (80KB) + sg (80KB) = 160KB LDS -> 1 block/CU
#define BPB  2         // clause-chunks per batch element -> grid 256 = 1/CU

typedef int   int4v   __attribute__((ext_vector_type(4)));
typedef float float4v __attribute__((ext_vector_type(4)));

__device__ __forceinline__ void clause_math(
    float a0, float a1, float a2, float xlv, float xsv, float zeta,
    float& C, float& g0, float& g1, float& g2)
{
    // top-2 with jax.lax.top_k tie semantics (first occurrence wins argmax)
    int k0; float m0, m1;
    if (a0 >= a1) {
        if (a0 >= a2) { k0 = 0; m0 = a0; m1 = fmaxf(a1, a2); }
        else          { k0 = 2; m0 = a2; m1 = fmaxf(a0, a1); }
    } else {
        if (a1 >= a2) { k0 = 1; m0 = a1; m1 = fmaxf(a0, a2); }
        else          { k0 = 2; m0 = a2; m1 = fmaxf(a0, a1); }
    }
    C = (1.f - m0) * 0.5f;
    const float T2 = (1.f - m1) * 0.5f;
    const float gl = xlv * xsv;
    const float rC = C * ((1.f + zeta * xlv) * (1.f - xsv));
    g0 = (k0 == 0 ? T2 : C) * gl + (k0 == 0 ? rC : 0.f);
    g1 = (k0 == 1 ? T2 : C) * gl + (k0 == 1 ? rC : 0.f);
    g2 = (k0 == 2 ? T2 : C) * gl + (k0 == 2 ? rC : 0.f);
}

// ---------- fast path: v + grad in LDS, burst-loaded 2x4 clause groups ----------
__global__ __launch_bounds__(1024, 4) void or_priv7(
    const float* __restrict__ v,
    const float* __restrict__ xl,
    const float* __restrict__ xs,
    const float* __restrict__ param,
    const float* __restrict__ sign,
    const int*   __restrict__ idx,
    float* __restrict__ outC,
    float* __restrict__ outdxl,
    float* __restrict__ outdxs,
    float* __restrict__ partial,   // [BPB][B][N]
    int N, int M, int B, int chunk)
{
    __shared__ float sv[NMAX];   // v slice (gathers stay in LDS -- R1 lesson)
    __shared__ float sg[NMAX];   // grad accumulator (stays in LDS -- R3 lesson)

    // XCD swizzle: the BPB=2 blocks of each b land on one XCD (v-stage L2 reuse)
    const int id  = blockIdx.x;
    const int cpx = gridDim.x >> 3;
    const int cid = ((gridDim.x & 7) == 0) ? ((id & 7) * cpx + (id >> 3)) : id;
    const int b   = cid >> 1;              // BPB == 2
    const int j   = cid & 1;
    const int tid = threadIdx.x;

    // stage v slice (coalesced float4) + zero grad
    {
        const float4v* __restrict__ v4 = (const float4v*)(v + (size_t)b * N);
        float4v* sv4 = (float4v*)sv;
        float4v* sg4 = (float4v*)sg;
        const int n4 = N >> 2;
        const float4v z = {0.f, 0.f, 0.f, 0.f};
        for (int i = tid; i < n4; i += 1024) {
            sv4[i] = v4[i];
            sg4[i] = z;
        }
        for (int i = (n4 << 2) + tid; i < N; i += 1024) {
            sv[i] = v[(size_t)b * N + i];
            sg[i] = 0.f;
        }
    }
    __syncthreads();

    const float alpha = param[0], beta = param[1], gamma = param[2];
    const float delta = param[3], eps  = param[4], zeta  = param[5];

    const int mstart = j * chunk;                 // chunk is a multiple of 4
    const int mend   = min(M, mstart + chunk);
    const int mlen   = mend - mstart;

    // burst-load a 4-clause group's streams (R2's proven nt dwordx4 pattern)
    #define GLOAD(G, gg) do {                                               \
        const size_t _base = (size_t)b * M + mstart + ((size_t)(gg) << 2);  \
        const int4v*   __restrict__ _ip = (const int4v*)(idx + _base * 3);  \
        const float4v* __restrict__ _sp = (const float4v*)(sign + _base * 3); \
        G##ia = __builtin_nontemporal_load(_ip + 0);                        \
        G##ib = __builtin_nontemporal_load(_ip + 1);                        \
        G##ic = __builtin_nontemporal_load(_ip + 2);                        \
        G##sa = __builtin_nontemporal_load(_sp + 0);                        \
        G##sb = __builtin_nontemporal_load(_sp + 1);                        \
        G##sc = __builtin_nontemporal_load(_sp + 2);                        \
        G##xl4 = __builtin_nontemporal_load((const float4v*)(xl + _base));  \
        G##xs4 = __builtin_nontemporal_load((const float4v*)(xs + _base));  \
    } while (0)

    // process a 4-clause group (identical math/order to the R2 winner)
    #define GPROC(G, gg) do {                                               \
        const size_t _base = (size_t)b * M + mstart + ((size_t)(gg) << 2);  \
        const int   _ii[12] = {G##ia.x, G##ia.y, G##ia.z, G##ia.w,          \
                               G##ib.x, G##ib.y, G##ib.z, G##ib.w,          \
                               G##ic.x, G##ic.y, G##ic.z, G##ic.w};         \
        const float _ss[12] = {G##sa.x, G##sa.y, G##sa.z, G##sa.w,          \
                               G##sb.x, G##sb.y, G##sb.z, G##sb.w,          \
                               G##sc.x, G##sc.y, G##sc.z, G##sc.w};         \
        const float _xlA[4] = {G##xl4.x, G##xl4.y, G##xl4.z, G##xl4.w};     \
        const float _xsA[4] = {G##xs4.x, G##xs4.y, G##xs4.z, G##xs4.w};     \
        float _Cv[4], _dxlv[4], _dxsv[4];                                   \
        _Pragma("unroll")                                                   \
        for (int c = 0; c < 4; ++c) {                                       \
            const int   _i0 = _ii[3*c], _i1 = _ii[3*c+1], _i2 = _ii[3*c+2]; \
            const float _s0 = _ss[3*c], _s1 = _ss[3*c+1], _s2 = _ss[3*c+2]; \
            const float _a0 = sv[_i0] * _s0;                                \
            const float _a1 = sv[_i1] * _s1;                                \
            const float _a2 = sv[_i2] * _s2;                                \
            float _C, _g0, _g1, _g2;                                        \
            clause_math(_a0, _a1, _a2, _xlA[c], _xsA[c], zeta,              \
                        _C, _g0, _g1, _g2);                                 \
            unsafeAtomicAdd(&sg[_i0], -_g0 * _s0);                          \
            unsafeAtomicAdd(&sg[_i1], -_g1 * _s1);                          \
            unsafeAtomicAdd(&sg[_i2], -_g2 * _s2);                          \
            _Cv[c]   = _C;                                                  \
            _dxlv[c] = -alpha * (_C - delta);                               \
            _dxsv[c] = -beta * (_xsA[c] + eps) * (_C - gamma);              \
        }                                                                   \
        const float4v _cv  = {_Cv[0], _Cv[1], _Cv[2], _Cv[3]};              \
        const float4v _lv  = {_dxlv[0], _dxlv[1], _dxlv[2], _dxlv[3]};      \
        const float4v _svo = {_dxsv[0], _dxsv[1], _dxsv[2], _dxsv[3]};      \
        __builtin_nontemporal_store(_cv,  (float4v*)(outC + _base));        \
        __builtin_nontemporal_store(_lv,  (float4v*)(outdxl + _base));      \
        __builtin_nontemporal_store(_svo, (float4v*)(outdxs + _base));      \
    } while (0)

    if (mlen > 0 && (mlen & 3) == 0) {
        const int ngroups = mlen >> 2;
        // each thread: two independent groups per iteration (g, g+1024).
        // ALL 16 loads issue before the barrier -> real in-flight MLP the
        // scheduler cannot collapse (data is live across the barrier).
        for (int g = tid; g < ngroups; g += 2048) {
            const int g1 = g + 1024;
            const bool has1 = (g1 < ngroups);

            int4v   Aia, Aib, Aic;         // group A registers (static names)
            float4v Asa, Asb, Asc, Axl4, Axs4;
            int4v   Bia, Bib, Bic;         // group B registers
            float4v Bsa, Bsb, Bsc, Bxl4, Bxs4;

            GLOAD(A, g);
            if (has1) GLOAD(B, g1);

            __builtin_amdgcn_sched_barrier(0);   // burst stays above compute

            GPROC(A, g);
            if (has1) GPROC(B, g1);
        }
    } else {
        // ragged tail fallback (not hit for M%4==0 shapes)
        for (int m = mstart + tid; m < mend; m += 1024) {
            const size_t bm  = (size_t)b * M + m;
            const size_t bm3 = bm * 3;
            const int   i0 = idx[bm3 + 0], i1 = idx[bm3 + 1], i2 = idx[bm3 + 2];
            const float s0 = sign[bm3 + 0], s1 = sign[bm3 + 1], s2 = sign[bm3 + 2];
            const float a0 = sv[i0] * s0, a1 = sv[i1] * s1, a2 = sv[i2] * s2;
            const float xlv = xl[bm], xsv = xs[bm];
            float C, g0, g1, g2;
            clause_math(a0, a1, a2, xlv, xsv, zeta, C, g0, g1, g2);
            unsafeAtomicAdd(&sg[i0], -g0 * s0);
            unsafeAtomicAdd(&sg[i1], -g1 * s1);
            unsafeAtomicAdd(&sg[i2], -g2 * s2);
            outC[bm]   = C;
            outdxl[bm] = -alpha * (C - delta);
            outdxs[bm] = -beta * (xsv + eps) * (C - gamma);
        }
    }
    #undef GLOAD
    #undef GPROC

    __syncthreads();

    // flush grad accumulator to the per-(j,b) partial slab (cached stores:
    // reduce2 then hits L2/L3 instead of HBM)
    {
        float* __restrict__ pj = partial + ((size_t)j * B + b) * N;
        const float4v* sg4 = (const float4v*)sg;
        const int n4 = N >> 2;
        for (int i = tid; i < n4; i += 1024)
            ((float4v*)pj)[i] = sg4[i];
        for (int i = (n4 << 2) + tid; i < N; i += 1024) pj[i] = sg[i];
    }
}

__global__ __launch_bounds__(256) void reduce2(
    const float4v* __restrict__ p, float4v* __restrict__ out, int n4, int stride4)
{
    int i = blockIdx.x * 256 + threadIdx.x;
    const int gs = gridDim.x * 256;
    for (; i < n4; i += gs) {
        const float4v a = p[i];
        const float4v b = p[i + stride4];
        out[i] = a + b;
    }
}

// ---------- fallback path (round-1, global atomics) ----------
__global__ __launch_bounds__(256) void zero_f4(float4v* __restrict__ p, int n4) {
    int i = blockIdx.x * blockDim.x + threadIdx.x;
    int stride = gridDim.x * blockDim.x;
    const float4v z = {0.f, 0.f, 0.f, 0.f};
    for (; i < n4; i += stride) p[i] = z;
}

__global__ __launch_bounds__(256) void or_kernel(
    const float* __restrict__ v, const float* __restrict__ xl,
    const float* __restrict__ xs, const float* __restrict__ param,
    const float* __restrict__ sign, const int* __restrict__ idx,
    float* __restrict__ outC, float* __restrict__ gradv,
    float* __restrict__ outdxl, float* __restrict__ outdxs, int N, int M)
{
    const int m = blockIdx.x * blockDim.x + threadIdx.x;
    const int b = blockIdx.y;
    if (m >= M) return;
    const size_t bm = (size_t)b * M + m;
    const size_t bm3 = bm * 3;
    const int   i0 = idx[bm3 + 0], i1 = idx[bm3 + 1], i2 = idx[bm3 + 2];
    const float s0 = sign[bm3 + 0], s1 = sign[bm3 + 1], s2 = sign[bm3 + 2];
    const float* __restrict__ vb = v + (size_t)b * N;
    const float a0 = vb[i0] * s0, a1 = vb[i1] * s1, a2 = vb[i2] * s2;
    const float xlv = xl[bm], xsv = xs[bm];
    const float alpha = param[0], beta = param[1], gamma = param[2];
    const float delta = param[3], eps  = param[4], zeta  = param[5];

    float C, g0, g1, g2;
    clause_math(a0, a1, a2, xlv, xsv, zeta, C, g0, g1, g2);

    float* __restrict__ gb = gradv + (size_t)b * N;
    atomicAdd(&gb[i0], -g0 * s0);
    atomicAdd(&gb[i1], -g1 * s1);
    atomicAdd(&gb[i2], -g2 * s2);

    outC[bm]   = C;
    outdxl[bm] = -alpha * (C - delta);
    outdxs[bm] = -beta * (xsv + eps) * (C - gamma);
}

extern "C" void kernel_launch(void* const* d_in, const int* in_sizes, int n_in,
                              void* d_out, int out_size, void* d_ws, size_t ws_size,
                              hipStream_t stream) {
    const float* v     = (const float*)d_in[0];
    const float* xl    = (const float*)d_in[1];
    const float* xs    = (const float*)d_in[2];
    const float* param = (const float*)d_in[3];
    const float* sign  = (const float*)d_in[4];
    const int*   idx   = (const int*)d_in[5];

    const int B = 128;
    const int N = in_sizes[0] / B;   // 20000
    const int M = in_sizes[1] / B;   // 85400

    float* outC   = (float*)d_out;
    float* gradv  = outC   + (size_t)in_sizes[1];
    float* outdxl = gradv  + (size_t)in_sizes[0];
    float* outdxs = outdxl + (size_t)in_sizes[1];

    const size_t bn = (size_t)B * N;
    const size_t ws_need = (size_t)BPB * bn * sizeof(float);

    if (N <= NMAX && ws_size >= ws_need && (bn % 4) == 0) {
        float* partial = (float*)d_ws;
        const int chunk = (((M + BPB - 1) / BPB) + 3) & ~3;
        or_priv7<<<dim3(BPB * B), dim3(1024), 0, stream>>>(
            v, xl, xs, param, sign, idx, outC, outdxl, outdxs,
            (float*)partial, N, M, B, chunk);
        const int n4 = (int)(bn / 4);
        const int rblocks = min(2048, (n4 + 255) / 256);
        reduce2<<<dim3(rblocks), dim3(256), 0, stream>>>(
            (const float4v*)partial, (float4v*)gradv, n4, n4);
    } else {
        const int n4 = (int)(bn / 4);
        zero_f4<<<dim3((n4 + 255) / 256), dim3(256), 0, stream>>>((float4v*)gradv, n4);
        dim3 grid((M + 255) / 256, B);
        or_kernel<<<grid, dim3(256), 0, stream>>>(v, xl, xs, param, sign, idx,
                                                  outC, gradv, outdxl, outdxs, N, M);
    }
}

// Round 6
// 455.676 us; speedup vs baseline: 1.0081x; 1.0081x over previous
//
#include <hip/hip_runtime.h>

// B=128 trajectories, N=20000 vars, M=85400 clauses, K=3 literals/clause.
// Inputs: v(B*N) f32, xl(B*M) f32, xs(B*M) f32, param(6) f32,
//         input_sign(B*M*K) f32, input_idx(B*M*K) i32
// Outputs concat: C(B*M), grad_v(B*N), dxl(B*M), dxs(B*M)  -- all f32

#define NMAX 20000     // sv (80KB) + sg (80KB) = 160KB LDS -> 1 block/CU
#define BPB  2         // clause-chunks per batch element -> grid 256 = 1/CU

typedef int   int4v   __attribute__((ext_vector_type(4)));
typedef float float4v __attribute__((ext_vector_type(4)));

__device__ __forceinline__ void clause_math(
    float a0, float a1, float a2, float xlv, float xsv, float zeta,
    float& C, float& g0, float& g1, float& g2)
{
    // top-2 with jax.lax.top_k tie semantics (first occurrence wins argmax)
    int k0; float m0, m1;
    if (a0 >= a1) {
        if (a0 >= a2) { k0 = 0; m0 = a0; m1 = fmaxf(a1, a2); }
        else          { k0 = 2; m0 = a2; m1 = fmaxf(a0, a1); }
    } else {
        if (a1 >= a2) { k0 = 1; m0 = a1; m1 = fmaxf(a0, a2); }
        else          { k0 = 2; m0 = a2; m1 = fmaxf(a0, a1); }
    }
    C = (1.f - m0) * 0.5f;
    const float T2 = (1.f - m1) * 0.5f;
    const float gl = xlv * xsv;
    const float rC = C * ((1.f + zeta * xlv) * (1.f - xsv));
    g0 = (k0 == 0 ? T2 : C) * gl + (k0 == 0 ? rC : 0.f);
    g1 = (k0 == 1 ? T2 : C) * gl + (k0 == 1 ? rC : 0.f);
    g2 = (k0 == 2 ? T2 : C) * gl + (k0 == 2 ? rC : 0.f);
}

// one 4-clause burst: 8x global_load_dwordx4 held in asm-pinned registers
struct G4 { int4v ia, ib, ic; float4v sa, sb, sc, xl4, xs4; };

// issue the 8 loads (compiler cannot sink/collapse: volatile asm, "=&v" regs)
__device__ __forceinline__ void g4_issue(G4& q,
    const int* __restrict__ ip, const float* __restrict__ sp,
    const float* __restrict__ xlp, const float* __restrict__ xsp,
    int off48, int off16)
{
    asm volatile(
        "global_load_dwordx4 %0, %8, %10\n\t"
        "global_load_dwordx4 %1, %8, %10 offset:16\n\t"
        "global_load_dwordx4 %2, %8, %10 offset:32\n\t"
        "global_load_dwordx4 %3, %8, %11\n\t"
        "global_load_dwordx4 %4, %8, %11 offset:16\n\t"
        "global_load_dwordx4 %5, %8, %11 offset:32\n\t"
        "global_load_dwordx4 %6, %9, %12\n\t"
        "global_load_dwordx4 %7, %9, %13\n\t"
        : "=&v"(q.ia), "=&v"(q.ib), "=&v"(q.ic),
          "=&v"(q.sa), "=&v"(q.sb), "=&v"(q.sc),
          "=&v"(q.xl4), "=&v"(q.xs4)
        : "v"(off48), "v"(off16), "s"(ip), "s"(sp), "s"(xlp), "s"(xsp));
}

// counted wait: 2 bursts (16 loads) stay in flight. Burst regs are "+v" ties,
// so every consumer of q is dataflow-ordered after the wait (rule-#18 safe).
__device__ __forceinline__ void g4_wait16(G4& q)
{
    asm volatile("s_waitcnt vmcnt(16)"
        : "+v"(q.ia), "+v"(q.ib), "+v"(q.ic),
          "+v"(q.sa), "+v"(q.sb), "+v"(q.sc),
          "+v"(q.xl4), "+v"(q.xs4));
}

// ---------- fast path: v + grad in LDS, asm ring-3 pipelined streams ----------
__global__ __launch_bounds__(1024, 4) void or_priv8(
    const float* __restrict__ v,
    const float* __restrict__ xl,
    const float* __restrict__ xs,
    const float* __restrict__ param,
    const float* __restrict__ sign,
    const int*   __restrict__ idx,
    float* __restrict__ outC,
    float* __restrict__ outdxl,
    float* __restrict__ outdxs,
    float* __restrict__ partial,   // [BPB][B][N]
    int N, int M, int B, int chunk)
{
    __shared__ float sv[NMAX];   // v slice (gathers stay in LDS -- R1 lesson)
    __shared__ float sg[NMAX];   // grad accumulator (stays in LDS -- R3 lesson)

    // XCD swizzle: the BPB=2 blocks of each b land on one XCD (v-stage L2 reuse)
    const int id  = blockIdx.x;
    const int cpx = gridDim.x >> 3;
    const int cid = ((gridDim.x & 7) == 0) ? ((id & 7) * cpx + (id >> 3)) : id;
    const int b   = cid >> 1;              // BPB == 2
    const int j   = cid & 1;
    const int tid = threadIdx.x;

    // stage v slice (coalesced float4) + zero grad
    {
        const float4v* __restrict__ v4 = (const float4v*)(v + (size_t)b * N);
        float4v* sv4 = (float4v*)sv;
        float4v* sg4 = (float4v*)sg;
        const int n4 = N >> 2;
        const float4v z = {0.f, 0.f, 0.f, 0.f};
        for (int i = tid; i < n4; i += 1024) {
            sv4[i] = v4[i];
            sg4[i] = z;
        }
        for (int i = (n4 << 2) + tid; i < N; i += 1024) {
            sv[i] = v[(size_t)b * N + i];
            sg[i] = 0.f;
        }
    }
    __syncthreads();

    const float alpha = param[0], beta = param[1], gamma = param[2];
    const float delta = param[3], eps  = param[4], zeta  = param[5];

    const int mstart = j * chunk;                 // chunk is a multiple of 4
    const int mend   = min(M, mstart + chunk);
    const int mlen   = mend - mstart;

    // process one burst: 4 clauses, LDS gather + clause math + LDS atomic + nt stores
    #define PROC_G4(Q, GG) do {                                              \
        const int   _i0a = (Q).ia.x, _i1a = (Q).ia.y, _i2a = (Q).ia.z;       \
        const int   _i0b = (Q).ia.w, _i1b = (Q).ib.x, _i2b = (Q).ib.y;       \
        const int   _i0c = (Q).ib.z, _i1c = (Q).ib.w, _i2c = (Q).ic.x;       \
        const int   _i0d = (Q).ic.y, _i1d = (Q).ic.z, _i2d = (Q).ic.w;       \
        const float _s0a = (Q).sa.x, _s1a = (Q).sa.y, _s2a = (Q).sa.z;       \
        const float _s0b = (Q).sa.w, _s1b = (Q).sb.x, _s2b = (Q).sb.y;       \
        const float _s0c = (Q).sb.z, _s1c = (Q).sb.w, _s2c = (Q).sc.x;       \
        const float _s0d = (Q).sc.y, _s1d = (Q).sc.z, _s2d = (Q).sc.w;       \
        float _C0, _g00, _g10, _g20;                                         \
        clause_math(sv[_i0a]*_s0a, sv[_i1a]*_s1a, sv[_i2a]*_s2a,             \
                    (Q).xl4.x, (Q).xs4.x, zeta, _C0, _g00, _g10, _g20);      \
        unsafeAtomicAdd(&sg[_i0a], -_g00 * _s0a);                            \
        unsafeAtomicAdd(&sg[_i1a], -_g10 * _s1a);                            \
        unsafeAtomicAdd(&sg[_i2a], -_g20 * _s2a);                            \
        float _C1, _g01, _g11, _g21;                                         \
        clause_math(sv[_i0b]*_s0b, sv[_i1b]*_s1b, sv[_i2b]*_s2b,             \
                    (Q).xl4.y, (Q).xs4.y, zeta, _C1, _g01, _g11, _g21);      \
        unsafeAtomicAdd(&sg[_i0b], -_g01 * _s0b);                            \
        unsafeAtomicAdd(&sg[_i1b], -_g11 * _s1b);                            \
        unsafeAtomicAdd(&sg[_i2b], -_g21 * _s2b);                            \
        float _C2, _g02, _g12, _g22;                                         \
        clause_math(sv[_i0c]*_s0c, sv[_i1c]*_s1c, sv[_i2c]*_s2c,             \
                    (Q).xl4.z, (Q).xs4.z, zeta, _C2, _g02, _g12, _g22);      \
        unsafeAtomicAdd(&sg[_i0c], -_g02 * _s0c);                            \
        unsafeAtomicAdd(&sg[_i1c], -_g12 * _s1c);                            \
        unsafeAtomicAdd(&sg[_i2c], -_g22 * _s2c);                            \
        float _C3, _g03, _g13, _g23;                                         \
        clause_math(sv[_i0d]*_s0d, sv[_i1d]*_s1d, sv[_i2d]*_s2d,             \
                    (Q).xl4.w, (Q).xs4.w, zeta, _C3, _g03, _g13, _g23);      \
        unsafeAtomicAdd(&sg[_i0d], -_g03 * _s0d);                            \
        unsafeAtomicAdd(&sg[_i1d], -_g13 * _s1d);                            \
        unsafeAtomicAdd(&sg[_i2d], -_g23 * _s2d);                            \
        const float4v _cv  = {_C0, _C1, _C2, _C3};                           \
        const float4v _lv  = {-alpha * (_C0 - delta), -alpha * (_C1 - delta),\
                              -alpha * (_C2 - delta), -alpha * (_C3 - delta)};\
        const float4v _sv2 = {-beta * ((Q).xs4.x + eps) * (_C0 - gamma),     \
                              -beta * ((Q).xs4.y + eps) * (_C1 - gamma),     \
                              -beta * ((Q).xs4.z + eps) * (_C2 - gamma),     \
                              -beta * ((Q).xs4.w + eps) * (_C3 - gamma)};    \
        __builtin_nontemporal_store(_cv,  (float4v*)(oC + ((size_t)(GG) << 2))); \
        __builtin_nontemporal_store(_lv,  (float4v*)(oL + ((size_t)(GG) << 2))); \
        __builtin_nontemporal_store(_sv2, (float4v*)(oS + ((size_t)(GG) << 2))); \
    } while (0)

    if (mlen > 0 && (mlen & 3) == 0) {
        const int ngroups = mlen >> 2;
        const size_t eb = (size_t)b * M + mstart;      // element base (mult of 4)
        const int*   __restrict__ ip  = idx  + eb * 3;
        const float* __restrict__ sp  = sign + eb * 3;
        const float* __restrict__ xlp = xl + eb;
        const float* __restrict__ xsp = xs + eb;
        float* __restrict__ oC = outC   + eb;
        float* __restrict__ oL = outdxl + eb;
        float* __restrict__ oS = outdxs + eb;

        if (tid < ngroups) {
            const int gmax = ngroups - 1;
            G4 q0, q1, q2;
            {
                const int a0 = min(tid,        gmax);
                const int a1 = min(tid + 1024, gmax);
                const int a2 = min(tid + 2048, gmax);
                g4_issue(q0, ip, sp, xlp, xsp, a0 * 48, a0 * 16);
                g4_issue(q1, ip, sp, xlp, xsp, a1 * 48, a1 * 16);
                g4_issue(q2, ip, sp, xlp, xsp, a2 * 48, a2 * 16);
            }
            // ring-3, depth-2: wait(16) always drains the slot being consumed
            // (>=16 loads were issued after it, at prologue AND at tail thanks
            // to clamped re-issues), while keeping the two newer bursts in flight.
            for (int g = tid; ; ) {
                g4_wait16(q0);
                PROC_G4(q0, g);
                { const int nx = min(g + 3072, gmax);
                  g4_issue(q0, ip, sp, xlp, xsp, nx * 48, nx * 16); }
                g += 1024; if (g >= ngroups) break;

                g4_wait16(q1);
                PROC_G4(q1, g);
                { const int nx = min(g + 3072, gmax);
                  g4_issue(q1, ip, sp, xlp, xsp, nx * 48, nx * 16); }
                g += 1024; if (g >= ngroups) break;

                g4_wait16(q2);
                PROC_G4(q2, g);
                { const int nx = min(g + 3072, gmax);
                  g4_issue(q2, ip, sp, xlp, xsp, nx * 48, nx * 16); }
                g += 1024; if (g >= ngroups) break;
            }
            // drain: in-flight asm loads must not land on reallocated VGPRs
            asm volatile("s_waitcnt vmcnt(0)" ::: "memory");
        }
    } else {
        // ragged tail fallback (not hit for M%4==0 shapes)
        for (int m = mstart + tid; m < mend; m += 1024) {
            const size_t bm  = (size_t)b * M + m;
            const size_t bm3 = bm * 3;
            const int   i0 = idx[bm3 + 0], i1 = idx[bm3 + 1], i2 = idx[bm3 + 2];
            const float s0 = sign[bm3 + 0], s1 = sign[bm3 + 1], s2 = sign[bm3 + 2];
            const float a0 = sv[i0] * s0, a1 = sv[i1] * s1, a2 = sv[i2] * s2;
            const float xlv = xl[bm], xsv = xs[bm];
            float C, g0, g1, g2;
            clause_math(a0, a1, a2, xlv, xsv, zeta, C, g0, g1, g2);
            unsafeAtomicAdd(&sg[i0], -g0 * s0);
            unsafeAtomicAdd(&sg[i1], -g1 * s1);
            unsafeAtomicAdd(&sg[i2], -g2 * s2);
            outC[bm]   = C;
            outdxl[bm] = -alpha * (C - delta);
            outdxs[bm] = -beta * (xsv + eps) * (C - gamma);
        }
    }
    #undef PROC_G4

    __syncthreads();

    // flush grad accumulator to the per-(j,b) partial slab (cached stores:
    // reduce2 then hits L2/L3 instead of HBM)
    {
        float* __restrict__ pj = partial + ((size_t)j * B + b) * N;
        const float4v* sg4 = (const float4v*)sg;
        const int n4 = N >> 2;
        for (int i = tid; i < n4; i += 1024)
            ((float4v*)pj)[i] = sg4[i];
        for (int i = (n4 << 2) + tid; i < N; i += 1024) pj[i] = sg[i];
    }
}

__global__ __launch_bounds__(256) void reduce2(
    const float4v* __restrict__ p, float4v* __restrict__ out, int n4, int stride4)
{
    int i = blockIdx.x * 256 + threadIdx.x;
    const int gs = gridDim.x * 256;
    for (; i < n4; i += gs) {
        const float4v a = p[i];
        const float4v b = p[i + stride4];
        out[i] = a + b;
    }
}

// ---------- fallback path (round-1, global atomics) ----------
__global__ __launch_bounds__(256) void zero_f4(float4v* __restrict__ p, int n4) {
    int i = blockIdx.x * blockDim.x + threadIdx.x;
    int stride = gridDim.x * blockDim.x;
    const float4v z = {0.f, 0.f, 0.f, 0.f};
    for (; i < n4; i += stride) p[i] = z;
}

__global__ __launch_bounds__(256) void or_kernel(
    const float* __restrict__ v, const float* __restrict__ xl,
    const float* __restrict__ xs, const float* __restrict__ param,
    const float* __restrict__ sign, const int* __restrict__ idx,
    float* __restrict__ outC, float* __restrict__ gradv,
    float* __restrict__ outdxl, float* __restrict__ outdxs, int N, int M)
{
    const int m = blockIdx.x * blockDim.x + threadIdx.x;
    const int b = blockIdx.y;
    if (m >= M) return;
    const size_t bm = (size_t)b * M + m;
    const size_t bm3 = bm * 3;
    const int   i0 = idx[bm3 + 0], i1 = idx[bm3 + 1], i2 = idx[bm3 + 2];
    const float s0 = sign[bm3 + 0], s1 = sign[bm3 + 1], s2 = sign[bm3 + 2];
    const float* __restrict__ vb = v + (size_t)b * N;
    const float a0 = vb[i0] * s0, a1 = vb[i1] * s1, a2 = vb[i2] * s2;
    const float xlv = xl[bm], xsv = xs[bm];
    const float alpha = param[0], beta = param[1], gamma = param[2];
    const float delta = param[3], eps  = param[4], zeta  = param[5];

    float C, g0, g1, g2;
    clause_math(a0, a1, a2, xlv, xsv, zeta, C, g0, g1, g2);

    float* __restrict__ gb = gradv + (size_t)b * N;
    atomicAdd(&gb[i0], -g0 * s0);
    atomicAdd(&gb[i1], -g1 * s1);
    atomicAdd(&gb[i2], -g2 * s2);

    outC[bm]   = C;
    outdxl[bm] = -alpha * (C - delta);
    outdxs[bm] = -beta * (xsv + eps) * (C - gamma);
}

extern "C" void kernel_launch(void* const* d_in, const int* in_sizes, int n_in,
                              void* d_out, int out_size, void* d_ws, size_t ws_size,
                              hipStream_t stream) {
    const float* v     = (const float*)d_in[0];
    const float* xl    = (const float*)d_in[1];
    const float* xs    = (const float*)d_in[2];
    const float* param = (const float*)d_in[3];
    const float* sign  = (const float*)d_in[4];
    const int*   idx   = (const int*)d_in[5];

    const int B = 128;
    const int N = in_sizes[0] / B;   // 20000
    const int M = in_sizes[1] / B;   // 85400

    float* outC   = (float*)d_out;
    float* gradv  = outC   + (size_t)in_sizes[1];
    float* outdxl = gradv  + (size_t)in_sizes[0];
    float* outdxs = outdxl + (size_t)in_sizes[1];

    const size_t bn = (size_t)B * N;
    const size_t ws_need = (size_t)BPB * bn * sizeof(float);

    if (N <= NMAX && ws_size >= ws_need && (bn % 4) == 0) {
        float* partial = (float*)d_ws;
        const int chunk = (((M + BPB - 1) / BPB) + 3) & ~3;
        or_priv8<<<dim3(BPB * B), dim3(1024), 0, stream>>>(
            v, xl, xs, param, sign, idx, outC, outdxl, outdxs,
            (float*)partial, N, M, B, chunk);
        const int n4 = (int)(bn / 4);
        const int rblocks = min(2048, (n4 + 255) / 256);
        reduce2<<<dim3(rblocks), dim3(256), 0, stream>>>(
            (const float4v*)partial, (float4v*)gradv, n4, n4);
    } else {
        const int n4 = (int)(bn / 4);
        zero_f4<<<dim3((n4 + 255) / 256), dim3(256), 0, stream>>>((float4v*)gradv, n4);
        dim3 grid((M + 255) / 256, B);
        or_kernel<<<grid, dim3(256), 0, stream>>>(v, xl, xs, param, sign, idx,
                                                  outC, gradv, outdxl, outdxs, N, M);
    }
}

// Round 7
// 451.056 us; speedup vs baseline: 1.0185x; 1.0102x over previous
//
#include <hip/hip_runtime.h>

// B=128 trajectories, N=20000 vars, M=85400 clauses, K=3 literals/clause.
// Inputs: v(B*N) f32, xl(B*M) f32, xs(B*M) f32, param(6) f32,
//         input_sign(B*M*K) f32, input_idx(B*M*K) i32
// Outputs concat: C(B*M), grad_v(B*N), dxl(B*M), dxs(B*M)  -- all f32

#define NMAX 20000     // sv (80KB) + sg (80KB) = 160KB LDS -> 1 block/CU
#define BPB  2         // clause-chunks per batch element -> grid 256 = 1/CU
#define TPB  512       // 512 threads -> launch_bounds(512,2) -> 256 VGPR cap
                       // (R6 lesson: 1024 threads capped VGPR at 128 -> the
                       //  96-reg asm ring SPILLED to scratch -> vmcnt drains)

typedef int   int4v   __attribute__((ext_vector_type(4)));
typedef float float4v __attribute__((ext_vector_type(4)));

__device__ __forceinline__ void clause_math(
    float a0, float a1, float a2, float xlv, float xsv, float zeta,
    float& C, float& g0, float& g1, float& g2)
{
    // top-2 with jax.lax.top_k tie semantics (first occurrence wins argmax)
    int k0; float m0, m1;
    if (a0 >= a1) {
        if (a0 >= a2) { k0 = 0; m0 = a0; m1 = fmaxf(a1, a2); }
        else          { k0 = 2; m0 = a2; m1 = fmaxf(a0, a1); }
    } else {
        if (a1 >= a2) { k0 = 1; m0 = a1; m1 = fmaxf(a0, a2); }
        else          { k0 = 2; m0 = a2; m1 = fmaxf(a0, a1); }
    }
    C = (1.f - m0) * 0.5f;
    const float T2 = (1.f - m1) * 0.5f;
    const float gl = xlv * xsv;
    const float rC = C * ((1.f + zeta * xlv) * (1.f - xsv));
    g0 = (k0 == 0 ? T2 : C) * gl + (k0 == 0 ? rC : 0.f);
    g1 = (k0 == 1 ? T2 : C) * gl + (k0 == 1 ? rC : 0.f);
    g2 = (k0 == 2 ? T2 : C) * gl + (k0 == 2 ? rC : 0.f);
}

// one 4-clause burst: 8x global_load_dwordx4 held in asm-pinned registers.
// ALL stream loads live here: a single compiler-emitted load in the loop
// would inject a vmcnt wait that drains the whole hand-counted pipeline.
struct G4 { int4v ia, ib, ic; float4v sa, sb, sc, xl4, xs4; };

__device__ __forceinline__ void g4_issue(G4& q,
    const int* __restrict__ ip, const float* __restrict__ sp,
    const float* __restrict__ xlp, const float* __restrict__ xsp,
    int off48, int off16)
{
    asm volatile(
        "global_load_dwordx4 %0, %8, %10\n\t"
        "global_load_dwordx4 %1, %8, %10 offset:16\n\t"
        "global_load_dwordx4 %2, %8, %10 offset:32\n\t"
        "global_load_dwordx4 %3, %8, %11\n\t"
        "global_load_dwordx4 %4, %8, %11 offset:16\n\t"
        "global_load_dwordx4 %5, %8, %11 offset:32\n\t"
        "global_load_dwordx4 %6, %9, %12\n\t"
        "global_load_dwordx4 %7, %9, %13\n\t"
        : "=&v"(q.ia), "=&v"(q.ib), "=&v"(q.ic),
          "=&v"(q.sa), "=&v"(q.sb), "=&v"(q.sc),
          "=&v"(q.xl4), "=&v"(q.xs4)
        : "v"(off48), "v"(off16), "s"(ip), "s"(sp), "s"(xlp), "s"(xsp));
}

// counted wait: uniform vmcnt(16) never under-waits (prologue: 24 outstanding
// -> drains exactly the oldest burst; steady: keeps ~2 bursts in flight).
// Burst regs are "+v" ties -> consumers are dataflow-ordered (rule-#18 safe).
__device__ __forceinline__ void g4_wait16(G4& q)
{
    asm volatile("s_waitcnt vmcnt(16)"
        : "+v"(q.ia), "+v"(q.ib), "+v"(q.ic),
          "+v"(q.sa), "+v"(q.sb), "+v"(q.sc),
          "+v"(q.xl4), "+v"(q.xs4));
}

// ---------- fast path: v + grad in LDS, asm ring-3, spill-free VGPR budget ----------
__global__ __launch_bounds__(TPB, 2) void or_priv9(
    const float* __restrict__ v,
    const float* __restrict__ xl,
    const float* __restrict__ xs,
    const float* __restrict__ param,
    const float* __restrict__ sign,
    const int*   __restrict__ idx,
    float* __restrict__ outC,
    float* __restrict__ outdxl,
    float* __restrict__ outdxs,
    float* __restrict__ partial,   // [BPB][B][N]
    int N, int M, int B, int chunk)
{
    __shared__ float sv[NMAX];   // v slice (gathers stay in LDS -- R1 lesson)
    __shared__ float sg[NMAX];   // grad accumulator (stays in LDS -- R3 lesson)

    // XCD swizzle: the BPB=2 blocks of each b land on one XCD (v-stage L2 reuse)
    const int id  = blockIdx.x;
    const int cpx = gridDim.x >> 3;
    const int cid = ((gridDim.x & 7) == 0) ? ((id & 7) * cpx + (id >> 3)) : id;
    const int b   = cid >> 1;              // BPB == 2
    const int j   = cid & 1;
    const int tid = threadIdx.x;

    // stage v slice (coalesced float4) + zero grad
    {
        const float4v* __restrict__ v4 = (const float4v*)(v + (size_t)b * N);
        float4v* sv4 = (float4v*)sv;
        float4v* sg4 = (float4v*)sg;
        const int n4 = N >> 2;
        const float4v z = {0.f, 0.f, 0.f, 0.f};
        for (int i = tid; i < n4; i += TPB) {
            sv4[i] = v4[i];
            sg4[i] = z;
        }
        for (int i = (n4 << 2) + tid; i < N; i += TPB) {
            sv[i] = v[(size_t)b * N + i];
            sg[i] = 0.f;
        }
    }
    __syncthreads();

    const float alpha = param[0], beta = param[1], gamma = param[2];
    const float delta = param[3], eps  = param[4], zeta  = param[5];

    const int mstart = j * chunk;                 // chunk is a multiple of 4
    const int mend   = min(M, mstart + chunk);
    const int mlen   = mend - mstart;

    // process one burst: 4 clauses. LDS gather + clause math + LDS atomic +
    // C++ nt stores (stores never trigger mid-loop compiler vmcnt waits).
    #define PROC_G4(Q, GG) do {                                              \
        const int   _i0a = (Q).ia.x, _i1a = (Q).ia.y, _i2a = (Q).ia.z;       \
        const int   _i0b = (Q).ia.w, _i1b = (Q).ib.x, _i2b = (Q).ib.y;       \
        const int   _i0c = (Q).ib.z, _i1c = (Q).ib.w, _i2c = (Q).ic.x;       \
        const int   _i0d = (Q).ic.y, _i1d = (Q).ic.z, _i2d = (Q).ic.w;       \
        const float _s0a = (Q).sa.x, _s1a = (Q).sa.y, _s2a = (Q).sa.z;       \
        const float _s0b = (Q).sa.w, _s1b = (Q).sb.x, _s2b = (Q).sb.y;       \
        const float _s0c = (Q).sb.z, _s1c = (Q).sb.w, _s2c = (Q).sc.x;       \
        const float _s0d = (Q).sc.y, _s1d = (Q).sc.z, _s2d = (Q).sc.w;       \
        float _C0, _g00, _g10, _g20;                                         \
        clause_math(sv[_i0a]*_s0a, sv[_i1a]*_s1a, sv[_i2a]*_s2a,             \
                    (Q).xl4.x, (Q).xs4.x, zeta, _C0, _g00, _g10, _g20);      \
        unsafeAtomicAdd(&sg[_i0a], -_g00 * _s0a);                            \
        unsafeAtomicAdd(&sg[_i1a], -_g10 * _s1a);                            \
        unsafeAtomicAdd(&sg[_i2a], -_g20 * _s2a);                            \
        float _C1, _g01, _g11, _g21;                                         \
        clause_math(sv[_i0b]*_s0b, sv[_i1b]*_s1b, sv[_i2b]*_s2b,             \
                    (Q).xl4.y, (Q).xs4.y, zeta, _C1, _g01, _g11, _g21);      \
        unsafeAtomicAdd(&sg[_i0b], -_g01 * _s0b);                            \
        unsafeAtomicAdd(&sg[_i1b], -_g11 * _s1b);                            \
        unsafeAtomicAdd(&sg[_i2b], -_g21 * _s2b);                            \
        float _C2, _g02, _g12, _g22;                                         \
        clause_math(sv[_i0c]*_s0c, sv[_i1c]*_s1c, sv[_i2c]*_s2c,             \
                    (Q).xl4.z, (Q).xs4.z, zeta, _C2, _g02, _g12, _g22);      \
        unsafeAtomicAdd(&sg[_i0c], -_g02 * _s0c);                            \
        unsafeAtomicAdd(&sg[_i1c], -_g12 * _s1c);                            \
        unsafeAtomicAdd(&sg[_i2c], -_g22 * _s2c);                            \
        float _C3, _g03, _g13, _g23;                                         \
        clause_math(sv[_i0d]*_s0d, sv[_i1d]*_s1d, sv[_i2d]*_s2d,             \
                    (Q).xl4.w, (Q).xs4.w, zeta, _C3, _g03, _g13, _g23);      \
        unsafeAtomicAdd(&sg[_i0d], -_g03 * _s0d);                            \
        unsafeAtomicAdd(&sg[_i1d], -_g13 * _s1d);                            \
        unsafeAtomicAdd(&sg[_i2d], -_g23 * _s2d);                            \
        const float4v _cv  = {_C0, _C1, _C2, _C3};                           \
        const float4v _lv  = {-alpha * (_C0 - delta), -alpha * (_C1 - delta),\
                              -alpha * (_C2 - delta), -alpha * (_C3 - delta)};\
        const float4v _sv2 = {-beta * ((Q).xs4.x + eps) * (_C0 - gamma),     \
                              -beta * ((Q).xs4.y + eps) * (_C1 - gamma),     \
                              -beta * ((Q).xs4.z + eps) * (_C2 - gamma),     \
                              -beta * ((Q).xs4.w + eps) * (_C3 - gamma)};    \
        __builtin_nontemporal_store(_cv,  (float4v*)(oC + ((size_t)(GG) << 2))); \
        __builtin_nontemporal_store(_lv,  (float4v*)(oL + ((size_t)(GG) << 2))); \
        __builtin_nontemporal_store(_sv2, (float4v*)(oS + ((size_t)(GG) << 2))); \
    } while (0)

    if (mlen > 0 && (mlen & 3) == 0) {
        const int ngroups = mlen >> 2;
        const size_t eb = (size_t)b * M + mstart;      // element base (mult of 4)
        const int*   __restrict__ ip  = idx  + eb * 3;
        const float* __restrict__ sp  = sign + eb * 3;
        const float* __restrict__ xlp = xl + eb;
        const float* __restrict__ xsp = xs + eb;
        float* __restrict__ oC = outC   + eb;
        float* __restrict__ oL = outdxl + eb;
        float* __restrict__ oS = outdxs + eb;

        if (tid < ngroups) {
            const int gmax = ngroups - 1;
            G4 q0, q1, q2;
            {
                const int a0 = min(tid,           gmax);
                const int a1 = min(tid + TPB,     gmax);
                const int a2 = min(tid + 2 * TPB, gmax);
                g4_issue(q0, ip, sp, xlp, xsp, a0 * 48, a0 * 16);
                g4_issue(q1, ip, sp, xlp, xsp, a1 * 48, a1 * 16);
                g4_issue(q2, ip, sp, xlp, xsp, a2 * 48, a2 * 16);
            }
            // ring-3: wait(16) drains exactly the slot being consumed while
            // keeping the two newer bursts in flight (clamped re-issues keep
            // the count valid at prologue AND tail).
            for (int g = tid; ; ) {
                g4_wait16(q0);
                PROC_G4(q0, g);
                { const int nx = min(g + 3 * TPB, gmax);
                  g4_issue(q0, ip, sp, xlp, xsp, nx * 48, nx * 16); }
                g += TPB; if (g >= ngroups) break;

                g4_wait16(q1);
                PROC_G4(q1, g);
                { const int nx = min(g + 3 * TPB, gmax);
                  g4_issue(q1, ip, sp, xlp, xsp, nx * 48, nx * 16); }
                g += TPB; if (g >= ngroups) break;

                g4_wait16(q2);
                PROC_G4(q2, g);
                { const int nx = min(g + 3 * TPB, gmax);
                  g4_issue(q2, ip, sp, xlp, xsp, nx * 48, nx * 16); }
                g += TPB; if (g >= ngroups) break;
            }
            // drain: in-flight asm loads must not land on reallocated VGPRs
            asm volatile("s_waitcnt vmcnt(0)" ::: "memory");
        }
    } else {
        // ragged tail fallback (not hit for M%4==0 shapes)
        for (int m = mstart + tid; m < mend; m += TPB) {
            const size_t bm  = (size_t)b * M + m;
            const size_t bm3 = bm * 3;
            const int   i0 = idx[bm3 + 0], i1 = idx[bm3 + 1], i2 = idx[bm3 + 2];
            const float s0 = sign[bm3 + 0], s1 = sign[bm3 + 1], s2 = sign[bm3 + 2];
            const float a0 = sv[i0] * s0, a1 = sv[i1] * s1, a2 = sv[i2] * s2;
            const float xlv = xl[bm], xsv = xs[bm];
            float C, g0, g1, g2;
            clause_math(a0, a1, a2, xlv, xsv, zeta, C, g0, g1, g2);
            unsafeAtomicAdd(&sg[i0], -g0 * s0);
            unsafeAtomicAdd(&sg[i1], -g1 * s1);
            unsafeAtomicAdd(&sg[i2], -g2 * s2);
            outC[bm]   = C;
            outdxl[bm] = -alpha * (C - delta);
            outdxs[bm] = -beta * (xsv + eps) * (C - gamma);
        }
    }
    #undef PROC_G4

    __syncthreads();

    // flush grad accumulator to the per-(j,b) partial slab (cached stores:
    // reduce2 then hits L2/L3 instead of HBM)
    {
        float* __restrict__ pj = partial + ((size_t)j * B + b) * N;
        const float4v* sg4 = (const float4v*)sg;
        const int n4 = N >> 2;
        for (int i = tid; i < n4; i += TPB)
            ((float4v*)pj)[i] = sg4[i];
        for (int i = (n4 << 2) + tid; i < N; i += TPB) pj[i] = sg[i];
    }
}

__global__ __launch_bounds__(256) void reduce2(
    const float4v* __restrict__ p, float4v* __restrict__ out, int n4, int stride4)
{
    int i = blockIdx.x * 256 + threadIdx.x;
    const int gs = gridDim.x * 256;
    for (; i < n4; i += gs) {
        const float4v a = p[i];
        const float4v b = p[i + stride4];
        out[i] = a + b;
    }
}

// ---------- fallback path (round-1, global atomics) ----------
__global__ __launch_bounds__(256) void zero_f4(float4v* __restrict__ p, int n4) {
    int i = blockIdx.x * blockDim.x + threadIdx.x;
    int stride = gridDim.x * blockDim.x;
    const float4v z = {0.f, 0.f, 0.f, 0.f};
    for (; i < n4; i += stride) p[i] = z;
}

__global__ __launch_bounds__(256) void or_kernel(
    const float* __restrict__ v, const float* __restrict__ xl,
    const float* __restrict__ xs, const float* __restrict__ param,
    const float* __restrict__ sign, const int* __restrict__ idx,
    float* __restrict__ outC, float* __restrict__ gradv,
    float* __restrict__ outdxl, float* __restrict__ outdxs, int N, int M)
{
    const int m = blockIdx.x * blockDim.x + threadIdx.x;
    const int b = blockIdx.y;
    if (m >= M) return;
    const size_t bm = (size_t)b * M + m;
    const size_t bm3 = bm * 3;
    const int   i0 = idx[bm3 + 0], i1 = idx[bm3 + 1], i2 = idx[bm3 + 2];
    const float s0 = sign[bm3 + 0], s1 = sign[bm3 + 1], s2 = sign[bm3 + 2];
    const float* __restrict__ vb = v + (size_t)b * N;
    const float a0 = vb[i0] * s0, a1 = vb[i1] * s1, a2 = vb[i2] * s2;
    const float xlv = xl[bm], xsv = xs[bm];
    const float alpha = param[0], beta = param[1], gamma = param[2];
    const float delta = param[3], eps  = param[4], zeta  = param[5];

    float C, g0, g1, g2;
    clause_math(a0, a1, a2, xlv, xsv, zeta, C, g0, g1, g2);

    float* __restrict__ gb = gradv + (size_t)b * N;
    atomicAdd(&gb[i0], -g0 * s0);
    atomicAdd(&gb[i1], -g1 * s1);
    atomicAdd(&gb[i2], -g2 * s2);

    outC[bm]   = C;
    outdxl[bm] = -alpha * (C - delta);
    outdxs[bm] = -beta * (xsv + eps) * (C - gamma);
}

extern "C" void kernel_launch(void* const* d_in, const int* in_sizes, int n_in,
                              void* d_out, int out_size, void* d_ws, size_t ws_size,
                              hipStream_t stream) {
    const float* v     = (const float*)d_in[0];
    const float* xl    = (const float*)d_in[1];
    const float* xs    = (const float*)d_in[2];
    const float* param = (const float*)d_in[3];
    const float* sign  = (const float*)d_in[4];
    const int*   idx   = (const int*)d_in[5];

    const int B = 128;
    const int N = in_sizes[0] / B;   // 20000
    const int M = in_sizes[1] / B;   // 85400

    float* outC   = (float*)d_out;
    float* gradv  = outC   + (size_t)in_sizes[1];
    float* outdxl = gradv  + (size_t)in_sizes[0];
    float* outdxs = outdxl + (size_t)in_sizes[1];

    const size_t bn = (size_t)B * N;
    const size_t ws_need = (size_t)BPB * bn * sizeof(float);

    if (N <= NMAX && ws_size >= ws_need && (bn % 4) == 0) {
        float* partial = (float*)d_ws;
        const int chunk = (((M + BPB - 1) / BPB) + 3) & ~3;
        or_priv9<<<dim3(BPB * B), dim3(TPB), 0, stream>>>(
            v, xl, xs, param, sign, idx, outC, outdxl, outdxs,
            (float*)partial, N, M, B, chunk);
        const int n4 = (int)(bn / 4);
        const int rblocks = min(2048, (n4 + 255) / 256);
        reduce2<<<dim3(rblocks), dim3(256), 0, stream>>>(
            (const float4v*)partial, (float4v*)gradv, n4, n4);
    } else {
        const int n4 = (int)(bn / 4);
        zero_f4<<<dim3((n4 + 255) / 256), dim3(256), 0, stream>>>((float4v*)gradv, n4);
        dim3 grid((M + 255) / 256, B);
        or_kernel<<<grid, dim3(256), 0, stream>>>(v, xl, xs, param, sign, idx,
                                                  outC, gradv, outdxl, outdxs, N, M);
    }
}